// Round 4
// baseline (811.244 us; speedup 1.0000x reference)
//
#include <hip/hip_runtime.h>
#include <math.h>

// Problem constants (B, N, TF, DM) = (16, 4096, 512, 1024)
#define B_DIM 16
#define N_SEQ 4096
#define TF_DIM 512
#define DM_DIM 1024
#define CHUNK 128
#define NCHUNK (N_SEQ / CHUNK)   // 32
#define NKT (DM_DIM / 32)        // 32 K-steps of BK=32

typedef __attribute__((ext_vector_type(4))) float f32x4;
typedef __attribute__((ext_vector_type(8))) short bf16x8;
typedef unsigned short u16;
typedef unsigned int u32;

__device__ __forceinline__ u16 f2bf(float f) {
    u32 u = __builtin_bit_cast(u32, f);
    u += 0x7fffu + ((u >> 16) & 1u);
    return (u16)(u >> 16);
}

__device__ __forceinline__ u32 cvtpk(float lo, float hi) {
    u32 r;
    asm("v_cvt_pk_bf16_f32 %0, %1, %2" : "=v"(r) : "v"(lo), "v"(hi));
    return r;
}

// Publish-barrier: order my LDS reads/writes before the barrier but leave
// global loads IN FLIGHT (no vmcnt drain — the whole point; __syncthreads
// would emit s_waitcnt vmcnt(0) and expose full HBM latency every step).
#define BARRIER_PUB() asm volatile("s_waitcnt lgkmcnt(0)\n\ts_barrier" ::: "memory")

// ---------------------------------------------------------------------------
// K1: u[m,f] = 2*x[m,f] - ( ls[m,:] . w[f,:] + bias[f] ),  m = b*N + n
// plus fused chunk-end EMA:  e[blockRow, f] = sum_j a*c^(127-j)*u[row0+j, f]
//
// 128x128 tile, BK=32, 4 waves (2x2), mfma_f32_16x16x32_bf16, bf16 LDS
// (reg-staged fp32->bf16 via v_cvt_pk_bf16_f32), XOR bank swizzle,
// double-buffered with counted-vmcnt pipeline: loads for tile t+2 issued
// before the barrier and waited (compiler vmcnt(8)) one full phase later.
// One raw s_barrier per K-step; lgkmcnt(0) only.
// ---------------------------------------------------------------------------
__global__ __launch_bounds__(256, 4)
void gemm_u_kernel(const float* __restrict__ x,
                   const float* __restrict__ ls,
                   const float* __restrict__ wmat,
                   const float* __restrict__ bias,
                   const float* __restrict__ alpha,
                   u16* __restrict__ u,
                   float* __restrict__ e)
{
    __shared__ unsigned short As[2][4096];  // 128 rows x 32 k (bf16), swizzled
    __shared__ unsigned short Ws[2][4096];
    __shared__ float red[2][4][16];         // cross-wave e-reduction

    const int tid  = threadIdx.x;
    const int f0   = blockIdx.x * 128;   // over TF (fast dim -> A-panel reuse)
    const int row0 = blockIdx.y * 128;   // over M = B*N; one (b,chunk) each

    const int lane = tid & 63;
    const int wid  = tid >> 6;
    const int wm = wid >> 1, wn = wid & 1;
    const int l15 = lane & 15, l4 = lane >> 4;

    // --- staging mapping: thread handles rows {srow, srow+64}, 8 k-elems each
    const int srow = tid >> 2;           // 0..63
    const int ke   = (tid & 3) * 8;      // 0,8,16,24
    const int sxor = (srow & 7) << 3;    // XOR swizzle (ushort units)
    const int sidx1 = (srow * 32 + ke) ^ sxor;
    const int sidx2 = ((srow + 64) * 32 + ke) ^ sxor;

    const float* aptr1 = ls   + (size_t)(row0 + srow) * DM_DIM + ke;
    const float* aptr2 = aptr1 + (size_t)64 * DM_DIM;
    const float* wptr1 = wmat + (size_t)(f0 + srow) * DM_DIM + ke;
    const float* wptr2 = wptr1 + (size_t)64 * DM_DIM;

    // --- fragment read offsets (ushort units), same XOR swizzle
    int rofa[4], rofw[4];
    const int rxor = (l15 & 7) << 3;
#pragma unroll
    for (int i = 0; i < 4; ++i) {
        rofa[i] = ((wm * 64 + i * 16 + l15) * 32 + l4 * 8) ^ rxor;
        rofw[i] = ((wn * 64 + i * 16 + l15) * 32 + l4 * 8) ^ rxor;
    }

    f32x4 acc[4][4];
#pragma unroll
    for (int i = 0; i < 4; ++i)
#pragma unroll
        for (int j = 0; j < 4; ++j) acc[i][j] = (f32x4){0.f, 0.f, 0.f, 0.f};

    // Two named staging sets (depth-2 prefetch; static names, no scratch)
    f32x4 A00, A01, A02, A03, W00, W01, W02, W03;
    f32x4 A10, A11, A12, A13, W10, W11, W12, W13;

#define LOAD_SET(SA, SW, KT) do {                                        \
        const int _ko = (KT) * 32;                                       \
        SA##0 = *(const f32x4*)(aptr1 + _ko);                            \
        SA##1 = *(const f32x4*)(aptr1 + _ko + 4);                        \
        SA##2 = *(const f32x4*)(aptr2 + _ko);                            \
        SA##3 = *(const f32x4*)(aptr2 + _ko + 4);                        \
        SW##0 = *(const f32x4*)(wptr1 + _ko);                            \
        SW##1 = *(const f32x4*)(wptr1 + _ko + 4);                        \
        SW##2 = *(const f32x4*)(wptr2 + _ko);                            \
        SW##3 = *(const f32x4*)(wptr2 + _ko + 4);                        \
    } while (0)

#define PACK8(V0, V1) ({                                                  \
        union { u32 u[4]; bf16x8 v; } _p;                                \
        _p.u[0] = cvtpk(V0[0], V0[1]);                                   \
        _p.u[1] = cvtpk(V0[2], V0[3]);                                   \
        _p.u[2] = cvtpk(V1[0], V1[1]);                                   \
        _p.u[3] = cvtpk(V1[2], V1[3]);                                   \
        _p.v; })

#define WRITE_SET(BUF, SA, SW) do {                                      \
        *(bf16x8*)(&As[BUF][sidx1]) = PACK8(SA##0, SA##1);               \
        *(bf16x8*)(&As[BUF][sidx2]) = PACK8(SA##2, SA##3);               \
        *(bf16x8*)(&Ws[BUF][sidx1]) = PACK8(SW##0, SW##1);               \
        *(bf16x8*)(&Ws[BUF][sidx2]) = PACK8(SW##2, SW##3);               \
    } while (0)

#define COMPUTE(BUF) do {                                                \
        const unsigned short* _Ab = As[BUF];                             \
        const unsigned short* _Wb = Ws[BUF];                             \
        bf16x8 _af[4], _wf[4];                                           \
        _Pragma("unroll")                                                \
        for (int i = 0; i < 4; ++i) {                                    \
            _af[i] = *(const bf16x8*)(_Ab + rofa[i]);                    \
            _wf[i] = *(const bf16x8*)(_Wb + rofw[i]);                    \
        }                                                                \
        _Pragma("unroll")                                                \
        for (int mi = 0; mi < 4; ++mi)                                   \
        _Pragma("unroll")                                                \
        for (int ni = 0; ni < 4; ++ni)                                   \
            acc[mi][ni] = __builtin_amdgcn_mfma_f32_16x16x32_bf16(       \
                _af[mi], _wf[ni], acc[mi][ni], 0, 0, 0);                 \
    } while (0)

    // prologue: tiles 0 and 1 in flight; publish tile 0
    LOAD_SET(A0, W0, 0);
    LOAD_SET(A1, W1, 1);
    WRITE_SET(0, A0, W0);
    BARRIER_PUB();

#pragma unroll 1
    for (int kt = 0; kt < NKT; kt += 2) {
        // step kt: compute buf0 (tile kt); publish buf1 (tile kt+1, regs A1);
        //          issue loads for tile kt+2 -> A0 (waited next step)
        if (kt + 2 < NKT) LOAD_SET(A0, W0, kt + 2);
        COMPUTE(0);
        WRITE_SET(1, A1, W1);          // compiler waits vmcnt for A1 only
        BARRIER_PUB();                 // loads for kt+2 remain in flight

        // step kt+1: compute buf1; publish buf0 (tile kt+2); load kt+3 -> A1
        if (kt + 3 < NKT) LOAD_SET(A1, W1, kt + 3);
        COMPUTE(1);
        if (kt + 2 < NKT) WRITE_SET(0, A0, W0);
        BARRIER_PUB();
    }

    // epilogue: u = 2x - (acc + bias) (stored bf16); fused chunk-end EMA
    const float a = 1.0f / (1.0f + expf(-alpha[0]));
    const float c = 1.0f - a;
    const float l2c = log2f(c);

    float bia[4];
#pragma unroll
    for (int ni = 0; ni < 4; ++ni) bia[ni] = bias[f0 + wn * 64 + ni * 16 + l15];

    float epart[4] = {0.f, 0.f, 0.f, 0.f};

#pragma unroll
    for (int mi = 0; mi < 4; ++mi) {
#pragma unroll
        for (int j = 0; j < 4; ++j) {
            const int r = wm * 64 + mi * 16 + l4 * 4 + j;   // row in chunk
            const size_t rb = (size_t)(row0 + r) * TF_DIM;
            const float wgt = (r == CHUNK - 1)
                                  ? a
                                  : a * exp2f((float)(CHUNK - 1 - r) * l2c);
#pragma unroll
            for (int ni = 0; ni < 4; ++ni) {
                const int f = f0 + wn * 64 + ni * 16 + l15;
                const float uval = 2.0f * x[rb + f] - (acc[mi][ni][j] + bia[ni]);
                u[rb + f] = f2bf(uval);
                epart[ni] = fmaf(wgt, uval, epart[ni]);
            }
        }
    }

    // reduce over l4 (shuffle) then over wm (LDS)
#pragma unroll
    for (int ni = 0; ni < 4; ++ni) {
        epart[ni] += __shfl_xor(epart[ni], 16, 64);
        epart[ni] += __shfl_xor(epart[ni], 32, 64);
    }
    if (wm == 1 && l4 == 0) {
#pragma unroll
        for (int ni = 0; ni < 4; ++ni) red[wn][ni][l15] = epart[ni];
    }
    __syncthreads();
    if (wm == 0 && l4 == 0) {
#pragma unroll
        for (int ni = 0; ni < 4; ++ni) {
            const int f = f0 + wn * 64 + ni * 16 + l15;
            e[(size_t)blockIdx.y * TF_DIM + f] = epart[ni] + red[wn][ni][l15];
        }
    }
}

// ---------------------------------------------------------------------------
// K3: serial carry scan over chunks per (b,f)
// ---------------------------------------------------------------------------
__global__ __launch_bounds__(256)
void ema_carry(const float* __restrict__ e, const float* __restrict__ alpha,
               float* __restrict__ carry)
{
    const int idx = blockIdx.x * 256 + threadIdx.x;  // b*TF + f
    const int f = idx & (TF_DIM - 1);
    const int b = idx >> 9;
    const float a = 1.0f / (1.0f + expf(-alpha[0]));
    const float c = 1.0f - a;
    const float cC = exp2f((float)CHUNK * log2f(c));  // c^CHUNK
    const size_t base = (size_t)b * NCHUNK * TF_DIM + f;
    float Y = 0.0f;
    carry[base] = 0.0f;
    for (int ch = 1; ch < NCHUNK; ++ch) {
        Y = fmaf(cC, Y, e[base + (size_t)(ch - 1) * TF_DIM]);
        carry[base + (size_t)ch * TF_DIM] = Y;
    }
}

// ---------------------------------------------------------------------------
// K4: apply chunk-local EMA with carry-in. u is bf16; each thread owns two
// adjacent f columns (uint load = 2 bf16, float2 store).
// ---------------------------------------------------------------------------
__global__ __launch_bounds__(256)
void ema_apply(const u16* __restrict__ u, const float* __restrict__ carry,
               const float* __restrict__ alpha, float* __restrict__ out)
{
    const int bc = blockIdx.x;                 // b*NCHUNK + ch, 0..511
    const int tid = threadIdx.x;               // owns f = 2*tid, 2*tid+1
    const float a = 1.0f / (1.0f + expf(-alpha[0]));
    const float c = 1.0f - a;
    float y0 = carry[(size_t)bc * TF_DIM + 2 * tid];
    float y1 = carry[(size_t)bc * TF_DIM + 2 * tid + 1];
    const u32* up = (const u32*)(u + (size_t)bc * CHUNK * TF_DIM) + tid;
    float2*    op = (float2*)(out + (size_t)bc * CHUNK * TF_DIM) + tid;
#pragma unroll 4
    for (int j = 0; j < CHUNK; ++j) {
        const u32 w = up[(size_t)j * (TF_DIM / 2)];
        const float u0 = __builtin_bit_cast(float, (w & 0xffffu) << 16);
        const float u1 = __builtin_bit_cast(float, (w >> 16) << 16);
        y0 = fmaf(c, y0, a * u0);
        y1 = fmaf(c, y1, a * u1);
        op[(size_t)j * (TF_DIM / 2)] = make_float2(y0, y1);
    }
}

extern "C" void kernel_launch(void* const* d_in, const int* in_sizes, int n_in,
                              void* d_out, int out_size, void* d_ws, size_t ws_size,
                              hipStream_t stream) {
    // setup_inputs order: x, latent_growth, latent_seasonal, alpha,
    //                     w_growth, b_growth, w_seasonal, b_seasonal
    const float* x     = (const float*)d_in[0];
    const float* ls    = (const float*)d_in[2];
    const float* alpha = (const float*)d_in[3];
    const float* wmat  = (const float*)d_in[6];
    const float* bias  = (const float*)d_in[7];
    float* out = (float*)d_out;

    u16*   u     = (u16*)d_ws;                                     // 67 MB bf16
    float* e     = (float*)(u + (size_t)B_DIM * N_SEQ * TF_DIM);   // 1 MB
    float* carry = e + (size_t)B_DIM * NCHUNK * TF_DIM;            // 1 MB

    dim3 g1(TF_DIM / 128, B_DIM * N_SEQ / 128);  // (4, 512) f-block fast
    gemm_u_kernel<<<g1, 256, 0, stream>>>(x, ls, wmat, bias, alpha, u, e);

    ema_carry<<<(B_DIM * TF_DIM) / 256, 256, 0, stream>>>(e, alpha, carry);
    ema_apply<<<B_DIM * NCHUNK, 256, 0, stream>>>(u, carry, alpha, out);
}

// Round 5
// 242.702 us; speedup vs baseline: 3.3426x; 3.3426x over previous
//
#include <hip/hip_runtime.h>
#include <math.h>

// Problem constants (B, N, TF, DM) = (16, 4096, 512, 1024)
#define B_DIM 16
#define N_SEQ 4096
#define TF_DIM 512
#define DM_DIM 1024
#define CHUNK 128
#define NCHUNK (N_SEQ / CHUNK)   // 32
#define NKT (DM_DIM / 32)        // 32 K-steps of BK=32

typedef __attribute__((ext_vector_type(4))) float f32x4;
typedef __attribute__((ext_vector_type(8))) short bf16x8;
typedef unsigned short u16;
typedef unsigned int u32;

__device__ __forceinline__ u16 f2bf(float f) {
    u32 u = __builtin_bit_cast(u32, f);
    u += 0x7fffu + ((u >> 16) & 1u);
    return (u16)(u >> 16);
}

__device__ __forceinline__ u32 cvtpk(float lo, float hi) {
    u32 r;
    asm("v_cvt_pk_bf16_f32 %0, %1, %2" : "=v"(r) : "v"(lo), "v"(hi));
    return r;
}

// Publish-barrier: order my LDS ops before the barrier but leave global
// loads IN FLIGHT (no vmcnt drain; __syncthreads would emit
// s_waitcnt vmcnt(0) and expose full HBM latency every step).
#define BARRIER_PUB() asm volatile("s_waitcnt lgkmcnt(0)\n\ts_barrier" ::: "memory")

// ---------------------------------------------------------------------------
// K1: u[m,f] = 2*x[m,f] - ( ls[m,:] . w[f,:] + bias[f] ),  m = b*N + n
// plus fused chunk-end EMA:  e[blockRow, f] = sum_j a*c^(127-j)*u[row0+j, f]
//
// 128x128 tile, BK=32, 4 waves (2x2), mfma_f32_16x16x32_bf16, bf16 LDS
// (reg-staged fp32->bf16 via v_cvt_pk_bf16_f32), XOR bank swizzle,
// depth-2 named-set register prefetch, counted-vmcnt pipeline: loads for
// tile t+2 issued before the barrier, waited (compiler vmcnt(8)) one full
// phase later. Raw s_barrier + lgkmcnt(0) only per K-step.
// __launch_bounds__(256,2): 100-VGPR regime, NO spills (round-4 lesson:
// (256,4) capped VGPR at 64 -> 1.5 GB scratch traffic, 3.4x regression).
// ---------------------------------------------------------------------------
__global__ __launch_bounds__(256, 2)
void gemm_u_kernel(const float* __restrict__ x,
                   const float* __restrict__ ls,
                   const float* __restrict__ wmat,
                   const float* __restrict__ bias,
                   const float* __restrict__ alpha,
                   u16* __restrict__ u,
                   float* __restrict__ e)
{
    __shared__ unsigned short As[2][4096];  // 128 rows x 32 k (bf16), swizzled
    __shared__ unsigned short Ws[2][4096];
    __shared__ float red[2][4][16];         // cross-wave e-reduction

    const int tid  = threadIdx.x;
    const int f0   = blockIdx.x * 128;   // over TF (fast dim -> A-panel reuse)
    const int row0 = blockIdx.y * 128;   // over M = B*N; one (b,chunk) each

    const int lane = tid & 63;
    const int wid  = tid >> 6;
    const int wm = wid >> 1, wn = wid & 1;
    const int l15 = lane & 15, l4 = lane >> 4;

    // --- staging mapping: thread handles rows {srow, srow+64}, 8 k-elems each
    const int srow = tid >> 2;           // 0..63
    const int ke   = (tid & 3) * 8;      // 0,8,16,24
    const int sxor = (srow & 7) << 3;    // XOR swizzle (ushort units)
    const int sidx1 = (srow * 32 + ke) ^ sxor;
    const int sidx2 = ((srow + 64) * 32 + ke) ^ sxor;

    const float* aptr1 = ls   + (size_t)(row0 + srow) * DM_DIM + ke;
    const float* aptr2 = aptr1 + (size_t)64 * DM_DIM;
    const float* wptr1 = wmat + (size_t)(f0 + srow) * DM_DIM + ke;
    const float* wptr2 = wptr1 + (size_t)64 * DM_DIM;

    // --- fragment read offsets (ushort units), same XOR swizzle
    int rofa[4], rofw[4];
    const int rxor = (l15 & 7) << 3;
#pragma unroll
    for (int i = 0; i < 4; ++i) {
        rofa[i] = ((wm * 64 + i * 16 + l15) * 32 + l4 * 8) ^ rxor;
        rofw[i] = ((wn * 64 + i * 16 + l15) * 32 + l4 * 8) ^ rxor;
    }

    f32x4 acc[4][4];
#pragma unroll
    for (int i = 0; i < 4; ++i)
#pragma unroll
        for (int j = 0; j < 4; ++j) acc[i][j] = (f32x4){0.f, 0.f, 0.f, 0.f};

    // Two named staging sets (depth-2 prefetch; static names, no scratch)
    f32x4 A00, A01, A02, A03, W00, W01, W02, W03;
    f32x4 A10, A11, A12, A13, W10, W11, W12, W13;

#define LOAD_SET(SA, SW, KT) do {                                        \
        const int _ko = (KT) * 32;                                       \
        SA##0 = *(const f32x4*)(aptr1 + _ko);                            \
        SA##1 = *(const f32x4*)(aptr1 + _ko + 4);                        \
        SA##2 = *(const f32x4*)(aptr2 + _ko);                            \
        SA##3 = *(const f32x4*)(aptr2 + _ko + 4);                        \
        SW##0 = *(const f32x4*)(wptr1 + _ko);                            \
        SW##1 = *(const f32x4*)(wptr1 + _ko + 4);                        \
        SW##2 = *(const f32x4*)(wptr2 + _ko);                            \
        SW##3 = *(const f32x4*)(wptr2 + _ko + 4);                        \
    } while (0)

#define PACK8(V0, V1) ({                                                  \
        union { u32 u[4]; bf16x8 v; } _p;                                \
        _p.u[0] = cvtpk(V0[0], V0[1]);                                   \
        _p.u[1] = cvtpk(V0[2], V0[3]);                                   \
        _p.u[2] = cvtpk(V1[0], V1[1]);                                   \
        _p.u[3] = cvtpk(V1[2], V1[3]);                                   \
        _p.v; })

#define WRITE_SET(BUF, SA, SW) do {                                      \
        *(bf16x8*)(&As[BUF][sidx1]) = PACK8(SA##0, SA##1);               \
        *(bf16x8*)(&As[BUF][sidx2]) = PACK8(SA##2, SA##3);               \
        *(bf16x8*)(&Ws[BUF][sidx1]) = PACK8(SW##0, SW##1);               \
        *(bf16x8*)(&Ws[BUF][sidx2]) = PACK8(SW##2, SW##3);               \
    } while (0)

#define COMPUTE(BUF) do {                                                \
        const unsigned short* _Ab = As[BUF];                             \
        const unsigned short* _Wb = Ws[BUF];                             \
        bf16x8 _af[4], _wf[4];                                           \
        _Pragma("unroll")                                                \
        for (int i = 0; i < 4; ++i) {                                    \
            _af[i] = *(const bf16x8*)(_Ab + rofa[i]);                    \
            _wf[i] = *(const bf16x8*)(_Wb + rofw[i]);                    \
        }                                                                \
        _Pragma("unroll")                                                \
        for (int mi = 0; mi < 4; ++mi)                                   \
        _Pragma("unroll")                                                \
        for (int ni = 0; ni < 4; ++ni)                                   \
            acc[mi][ni] = __builtin_amdgcn_mfma_f32_16x16x32_bf16(       \
                _af[mi], _wf[ni], acc[mi][ni], 0, 0, 0);                 \
    } while (0)

    // prologue: tiles 0 and 1 in flight; publish tile 0
    LOAD_SET(A0, W0, 0);
    LOAD_SET(A1, W1, 1);
    WRITE_SET(0, A0, W0);
    BARRIER_PUB();

#pragma unroll 1
    for (int kt = 0; kt < NKT; kt += 2) {
        // step kt: issue loads for tile kt+2 -> A0; compute buf0 (tile kt);
        //          publish buf1 (tile kt+1, regs A1 — vmcnt(8), A0 in flight)
        if (kt + 2 < NKT) LOAD_SET(A0, W0, kt + 2);
        COMPUTE(0);
        WRITE_SET(1, A1, W1);
        BARRIER_PUB();                 // loads for kt+2 remain in flight

        // step kt+1: compute buf1; publish buf0 (tile kt+2); load kt+3 -> A1
        if (kt + 3 < NKT) LOAD_SET(A1, W1, kt + 3);
        COMPUTE(1);
        if (kt + 2 < NKT) WRITE_SET(0, A0, W0);
        BARRIER_PUB();
    }

    // epilogue: u = 2x - (acc + bias) (stored bf16); fused chunk-end EMA
    const float a = 1.0f / (1.0f + expf(-alpha[0]));
    const float c = 1.0f - a;
    const float l2c = log2f(c);

    float bia[4];
#pragma unroll
    for (int ni = 0; ni < 4; ++ni) bia[ni] = bias[f0 + wn * 64 + ni * 16 + l15];

    float epart[4] = {0.f, 0.f, 0.f, 0.f};

#pragma unroll
    for (int mi = 0; mi < 4; ++mi) {
#pragma unroll
        for (int j = 0; j < 4; ++j) {
            const int r = wm * 64 + mi * 16 + l4 * 4 + j;   // row in chunk
            const size_t rb = (size_t)(row0 + r) * TF_DIM;
            const float wgt = (r == CHUNK - 1)
                                  ? a
                                  : a * exp2f((float)(CHUNK - 1 - r) * l2c);
#pragma unroll
            for (int ni = 0; ni < 4; ++ni) {
                const int f = f0 + wn * 64 + ni * 16 + l15;
                const float uval = 2.0f * x[rb + f] - (acc[mi][ni][j] + bia[ni]);
                u[rb + f] = f2bf(uval);
                epart[ni] = fmaf(wgt, uval, epart[ni]);
            }
        }
    }

    // reduce over l4 (shuffle) then over wm (LDS)
#pragma unroll
    for (int ni = 0; ni < 4; ++ni) {
        epart[ni] += __shfl_xor(epart[ni], 16, 64);
        epart[ni] += __shfl_xor(epart[ni], 32, 64);
    }
    if (wm == 1 && l4 == 0) {
#pragma unroll
        for (int ni = 0; ni < 4; ++ni) red[wn][ni][l15] = epart[ni];
    }
    __syncthreads();
    if (wm == 0 && l4 == 0) {
#pragma unroll
        for (int ni = 0; ni < 4; ++ni) {
            const int f = f0 + wn * 64 + ni * 16 + l15;
            e[(size_t)blockIdx.y * TF_DIM + f] = epart[ni] + red[wn][ni][l15];
        }
    }
}

// ---------------------------------------------------------------------------
// K3: serial carry scan over chunks per (b,f)
// ---------------------------------------------------------------------------
__global__ __launch_bounds__(256)
void ema_carry(const float* __restrict__ e, const float* __restrict__ alpha,
               float* __restrict__ carry)
{
    const int idx = blockIdx.x * 256 + threadIdx.x;  // b*TF + f
    const int f = idx & (TF_DIM - 1);
    const int b = idx >> 9;
    const float a = 1.0f / (1.0f + expf(-alpha[0]));
    const float c = 1.0f - a;
    const float cC = exp2f((float)CHUNK * log2f(c));  // c^CHUNK
    const size_t base = (size_t)b * NCHUNK * TF_DIM + f;
    float Y = 0.0f;
    carry[base] = 0.0f;
    for (int ch = 1; ch < NCHUNK; ++ch) {
        Y = fmaf(cC, Y, e[base + (size_t)(ch - 1) * TF_DIM]);
        carry[base + (size_t)ch * TF_DIM] = Y;
    }
}

// ---------------------------------------------------------------------------
// K4: apply chunk-local EMA with carry-in. u is bf16; each thread owns two
// adjacent f columns (uint load = 2 bf16, float2 store).
// ---------------------------------------------------------------------------
__global__ __launch_bounds__(256)
void ema_apply(const u16* __restrict__ u, const float* __restrict__ carry,
               const float* __restrict__ alpha, float* __restrict__ out)
{
    const int bc = blockIdx.x;                 // b*NCHUNK + ch, 0..511
    const int tid = threadIdx.x;               // owns f = 2*tid, 2*tid+1
    const float a = 1.0f / (1.0f + expf(-alpha[0]));
    const float c = 1.0f - a;
    float y0 = carry[(size_t)bc * TF_DIM + 2 * tid];
    float y1 = carry[(size_t)bc * TF_DIM + 2 * tid + 1];
    const u32* up = (const u32*)(u + (size_t)bc * CHUNK * TF_DIM) + tid;
    float2*    op = (float2*)(out + (size_t)bc * CHUNK * TF_DIM) + tid;
#pragma unroll 4
    for (int j = 0; j < CHUNK; ++j) {
        const u32 w = up[(size_t)j * (TF_DIM / 2)];
        const float u0 = __builtin_bit_cast(float, (w & 0xffffu) << 16);
        const float u1 = __builtin_bit_cast(float, (w >> 16) << 16);
        y0 = fmaf(c, y0, a * u0);
        y1 = fmaf(c, y1, a * u1);
        op[(size_t)j * (TF_DIM / 2)] = make_float2(y0, y1);
    }
}

extern "C" void kernel_launch(void* const* d_in, const int* in_sizes, int n_in,
                              void* d_out, int out_size, void* d_ws, size_t ws_size,
                              hipStream_t stream) {
    // setup_inputs order: x, latent_growth, latent_seasonal, alpha,
    //                     w_growth, b_growth, w_seasonal, b_seasonal
    const float* x     = (const float*)d_in[0];
    const float* ls    = (const float*)d_in[2];
    const float* alpha = (const float*)d_in[3];
    const float* wmat  = (const float*)d_in[6];
    const float* bias  = (const float*)d_in[7];
    float* out = (float*)d_out;

    u16*   u     = (u16*)d_ws;                                     // 67 MB bf16
    float* e     = (float*)(u + (size_t)B_DIM * N_SEQ * TF_DIM);   // 1 MB
    float* carry = e + (size_t)B_DIM * NCHUNK * TF_DIM;            // 1 MB

    dim3 g1(TF_DIM / 128, B_DIM * N_SEQ / 128);  // (4, 512) f-block fast
    gemm_u_kernel<<<g1, 256, 0, stream>>>(x, ls, wmat, bias, alpha, u, e);

    ema_carry<<<(B_DIM * TF_DIM) / 256, 256, 0, stream>>>(e, alpha, carry);
    ema_apply<<<B_DIM * NCHUNK, 256, 0, stream>>>(u, carry, alpha, out);
}

// Round 6
// 231.792 us; speedup vs baseline: 3.4999x; 1.0471x over previous
//
#include <hip/hip_runtime.h>
#include <math.h>

// Problem constants (B, N, TF, DM) = (16, 4096, 512, 1024)
#define B_DIM 16
#define N_SEQ 4096
#define TF_DIM 512
#define DM_DIM 1024
#define CHUNK 128
#define NCHUNK (N_SEQ / CHUNK)   // 32
#define NKT (DM_DIM / 32)        // 32 K-steps of BK=32

typedef __attribute__((ext_vector_type(4))) float f32x4;
typedef __attribute__((ext_vector_type(8))) short bf16x8;
typedef unsigned short u16;
typedef unsigned int u32;

__device__ __forceinline__ u16 f2bf(float f) {
    u32 u = __builtin_bit_cast(u32, f);
    u += 0x7fffu + ((u >> 16) & 1u);
    return (u16)(u >> 16);
}

__device__ __forceinline__ u32 cvtpk(float lo, float hi) {
    u32 r;
    asm("v_cvt_pk_bf16_f32 %0, %1, %2" : "=v"(r) : "v"(lo), "v"(hi));
    return r;
}

// Publish-barrier: order my LDS ops before the barrier but leave global
// loads IN FLIGHT (no vmcnt drain).
#define BARRIER_PUB() asm volatile("s_waitcnt lgkmcnt(0)\n\ts_barrier" ::: "memory")

// ---------------------------------------------------------------------------
// K1: u[m,f] = 2*x[m,f] - ( ls[m,:] . w[f,:] + bias[f] ),  m = b*N + n
// plus fused chunk-end EMA:  e[rowPanel, f] = sum_j a*c^(127-j)*u[row0+j, f]
//
// 128x128 tile, BK=32, 4 waves (2x2), mfma_f32_16x16x32_bf16, bf16 LDS
// (reg-staged fp32->bf16 via v_cvt_pk_bf16_f32), XOR bank swizzle,
// depth-2 named-set register prefetch, raw s_barrier + lgkmcnt(0) only.
//
// XCD-aware remap (round-6 lever): with linear dispatch the 4 f-sibling
// blocks sharing one A-row-panel land on 4 DIFFERENT XCDs (slot%8), so
// every A request misses the per-XCD L2 -> L3/HBM congestion (measured:
// 2.75 TB/s, phase stall ~3500cy). Remap slot s -> xcd-local sequence
// where the 4 f-siblings of each row-panel are consecutive ON ONE XCD:
//   x=s&7, k=s>>3, f=k&3, row=x+8*(k>>2)    (bijective, 2048 slots)
// A-panel then hits local L2 for 3 of 4 blocks.
// ---------------------------------------------------------------------------
__global__ __launch_bounds__(256, 2)
void gemm_u_kernel(const float* __restrict__ x,
                   const float* __restrict__ ls,
                   const float* __restrict__ wmat,
                   const float* __restrict__ bias,
                   const float* __restrict__ alpha,
                   u16* __restrict__ u,
                   float* __restrict__ e)
{
    __shared__ unsigned short As[2][4096];  // 128 rows x 32 k (bf16), swizzled
    __shared__ unsigned short Ws[2][4096];
    __shared__ float red[2][4][16];         // cross-wave e-reduction

    const int tid  = threadIdx.x;

    // XCD-aware decode of the dispatch slot
    const int s   = blockIdx.x;            // 0..2047, xcd ~ s&7
    const int kk  = s >> 3;
    const int fb  = kk & 3;                // f-block 0..3
    const int rp  = (s & 7) + ((kk >> 2) << 3);  // row-panel 0..511
    const int f0   = fb * 128;
    const int row0 = rp * 128;

    const int lane = tid & 63;
    const int wid  = tid >> 6;
    const int wm = wid >> 1, wn = wid & 1;
    const int l15 = lane & 15, l4 = lane >> 4;

    // --- staging mapping: thread handles rows {srow, srow+64}, 8 k-elems each
    const int srow = tid >> 2;           // 0..63
    const int ke   = (tid & 3) * 8;      // 0,8,16,24
    const int sxor = (srow & 7) << 3;    // XOR swizzle (ushort units)
    const int sidx1 = (srow * 32 + ke) ^ sxor;
    const int sidx2 = ((srow + 64) * 32 + ke) ^ sxor;

    const float* aptr1 = ls   + (size_t)(row0 + srow) * DM_DIM + ke;
    const float* aptr2 = aptr1 + (size_t)64 * DM_DIM;
    const float* wptr1 = wmat + (size_t)(f0 + srow) * DM_DIM + ke;
    const float* wptr2 = wptr1 + (size_t)64 * DM_DIM;

    // --- fragment read offsets (ushort units), same XOR swizzle
    int rofa[4], rofw[4];
    const int rxor = (l15 & 7) << 3;
#pragma unroll
    for (int i = 0; i < 4; ++i) {
        rofa[i] = ((wm * 64 + i * 16 + l15) * 32 + l4 * 8) ^ rxor;
        rofw[i] = ((wn * 64 + i * 16 + l15) * 32 + l4 * 8) ^ rxor;
    }

    f32x4 acc[4][4];
#pragma unroll
    for (int i = 0; i < 4; ++i)
#pragma unroll
        for (int j = 0; j < 4; ++j) acc[i][j] = (f32x4){0.f, 0.f, 0.f, 0.f};

    // Two named staging sets (depth-2 prefetch; static names, no scratch)
    f32x4 A00, A01, A02, A03, W00, W01, W02, W03;
    f32x4 A10, A11, A12, A13, W10, W11, W12, W13;

#define LOAD_SET(SA, SW, KT) do {                                        \
        const int _ko = (KT) * 32;                                       \
        SA##0 = *(const f32x4*)(aptr1 + _ko);                            \
        SA##1 = *(const f32x4*)(aptr1 + _ko + 4);                        \
        SA##2 = *(const f32x4*)(aptr2 + _ko);                            \
        SA##3 = *(const f32x4*)(aptr2 + _ko + 4);                        \
        SW##0 = *(const f32x4*)(wptr1 + _ko);                            \
        SW##1 = *(const f32x4*)(wptr1 + _ko + 4);                        \
        SW##2 = *(const f32x4*)(wptr2 + _ko);                            \
        SW##3 = *(const f32x4*)(wptr2 + _ko + 4);                        \
    } while (0)

#define PACK8(V0, V1) ({                                                  \
        union { u32 u[4]; bf16x8 v; } _p;                                \
        _p.u[0] = cvtpk(V0[0], V0[1]);                                   \
        _p.u[1] = cvtpk(V0[2], V0[3]);                                   \
        _p.u[2] = cvtpk(V1[0], V1[1]);                                   \
        _p.u[3] = cvtpk(V1[2], V1[3]);                                   \
        _p.v; })

#define WRITE_SET(BUF, SA, SW) do {                                      \
        *(bf16x8*)(&As[BUF][sidx1]) = PACK8(SA##0, SA##1);               \
        *(bf16x8*)(&As[BUF][sidx2]) = PACK8(SA##2, SA##3);               \
        *(bf16x8*)(&Ws[BUF][sidx1]) = PACK8(SW##0, SW##1);               \
        *(bf16x8*)(&Ws[BUF][sidx2]) = PACK8(SW##2, SW##3);               \
    } while (0)

#define COMPUTE(BUF) do {                                                \
        const unsigned short* _Ab = As[BUF];                             \
        const unsigned short* _Wb = Ws[BUF];                             \
        bf16x8 _af[4], _wf[4];                                           \
        _Pragma("unroll")                                                \
        for (int i = 0; i < 4; ++i) {                                    \
            _af[i] = *(const bf16x8*)(_Ab + rofa[i]);                    \
            _wf[i] = *(const bf16x8*)(_Wb + rofw[i]);                    \
        }                                                                \
        _Pragma("unroll")                                                \
        for (int mi = 0; mi < 4; ++mi)                                   \
        _Pragma("unroll")                                                \
        for (int ni = 0; ni < 4; ++ni)                                   \
            acc[mi][ni] = __builtin_amdgcn_mfma_f32_16x16x32_bf16(       \
                _af[mi], _wf[ni], acc[mi][ni], 0, 0, 0);                 \
    } while (0)

    // prologue: tiles 0 and 1 in flight; publish tile 0
    LOAD_SET(A0, W0, 0);
    LOAD_SET(A1, W1, 1);
    WRITE_SET(0, A0, W0);
    BARRIER_PUB();

#pragma unroll 1
    for (int kt = 0; kt < NKT; kt += 2) {
        // step kt: issue loads for tile kt+2 -> A0; compute buf0 (tile kt);
        //          publish buf1 (tile kt+1, regs A1 — vmcnt leaves A0 in flight)
        if (kt + 2 < NKT) LOAD_SET(A0, W0, kt + 2);
        COMPUTE(0);
        WRITE_SET(1, A1, W1);
        BARRIER_PUB();                 // loads for kt+2 remain in flight

        // step kt+1: compute buf1; publish buf0 (tile kt+2); load kt+3 -> A1
        if (kt + 3 < NKT) LOAD_SET(A1, W1, kt + 3);
        COMPUTE(1);
        if (kt + 2 < NKT) WRITE_SET(0, A0, W0);
        BARRIER_PUB();
    }

    // epilogue: u = 2x - (acc + bias) (stored bf16); fused chunk-end EMA
    const float a = 1.0f / (1.0f + expf(-alpha[0]));
    const float c = 1.0f - a;
    const float l2c = log2f(c);

    float bia[4];
#pragma unroll
    for (int ni = 0; ni < 4; ++ni) bia[ni] = bias[f0 + wn * 64 + ni * 16 + l15];

    float epart[4] = {0.f, 0.f, 0.f, 0.f};

#pragma unroll
    for (int mi = 0; mi < 4; ++mi) {
#pragma unroll
        for (int j = 0; j < 4; ++j) {
            const int r = wm * 64 + mi * 16 + l4 * 4 + j;   // row in chunk
            const size_t rb = (size_t)(row0 + r) * TF_DIM;
            const float wgt = (r == CHUNK - 1)
                                  ? a
                                  : a * exp2f((float)(CHUNK - 1 - r) * l2c);
#pragma unroll
            for (int ni = 0; ni < 4; ++ni) {
                const int f = f0 + wn * 64 + ni * 16 + l15;
                const float uval = 2.0f * x[rb + f] - (acc[mi][ni][j] + bia[ni]);
                u[rb + f] = f2bf(uval);
                epart[ni] = fmaf(wgt, uval, epart[ni]);
            }
        }
    }

    // reduce over l4 (shuffle) then over wm (LDS)
#pragma unroll
    for (int ni = 0; ni < 4; ++ni) {
        epart[ni] += __shfl_xor(epart[ni], 16, 64);
        epart[ni] += __shfl_xor(epart[ni], 32, 64);
    }
    if (wm == 1 && l4 == 0) {
#pragma unroll
        for (int ni = 0; ni < 4; ++ni) red[wn][ni][l15] = epart[ni];
    }
    __syncthreads();
    if (wm == 0 && l4 == 0) {
#pragma unroll
        for (int ni = 0; ni < 4; ++ni) {
            const int f = f0 + wn * 64 + ni * 16 + l15;
            e[(size_t)rp * TF_DIM + f] = epart[ni] + red[wn][ni][l15];
        }
    }
}

// ---------------------------------------------------------------------------
// K3: serial carry scan over chunks per (b,f)
// ---------------------------------------------------------------------------
__global__ __launch_bounds__(256)
void ema_carry(const float* __restrict__ e, const float* __restrict__ alpha,
               float* __restrict__ carry)
{
    const int idx = blockIdx.x * 256 + threadIdx.x;  // b*TF + f
    const int f = idx & (TF_DIM - 1);
    const int b = idx >> 9;
    const float a = 1.0f / (1.0f + expf(-alpha[0]));
    const float c = 1.0f - a;
    const float cC = exp2f((float)CHUNK * log2f(c));  // c^CHUNK
    const size_t base = (size_t)b * NCHUNK * TF_DIM + f;
    float Y = 0.0f;
    carry[base] = 0.0f;
    for (int ch = 1; ch < NCHUNK; ++ch) {
        Y = fmaf(cC, Y, e[base + (size_t)(ch - 1) * TF_DIM]);
        carry[base + (size_t)ch * TF_DIM] = Y;
    }
}

// ---------------------------------------------------------------------------
// K4: apply chunk-local EMA with carry-in. u is bf16; each thread owns two
// adjacent f columns (uint load = 2 bf16, float2 store).
// ---------------------------------------------------------------------------
__global__ __launch_bounds__(256)
void ema_apply(const u16* __restrict__ u, const float* __restrict__ carry,
               const float* __restrict__ alpha, float* __restrict__ out)
{
    const int bc = blockIdx.x;                 // b*NCHUNK + ch, 0..511
    const int tid = threadIdx.x;               // owns f = 2*tid, 2*tid+1
    const float a = 1.0f / (1.0f + expf(-alpha[0]));
    const float c = 1.0f - a;
    float y0 = carry[(size_t)bc * TF_DIM + 2 * tid];
    float y1 = carry[(size_t)bc * TF_DIM + 2 * tid + 1];
    const u32* up = (const u32*)(u + (size_t)bc * CHUNK * TF_DIM) + tid;
    float2*    op = (float2*)(out + (size_t)bc * CHUNK * TF_DIM) + tid;
#pragma unroll 4
    for (int j = 0; j < CHUNK; ++j) {
        const u32 w = up[(size_t)j * (TF_DIM / 2)];
        const float u0 = __builtin_bit_cast(float, (w & 0xffffu) << 16);
        const float u1 = __builtin_bit_cast(float, (w >> 16) << 16);
        y0 = fmaf(c, y0, a * u0);
        y1 = fmaf(c, y1, a * u1);
        op[(size_t)j * (TF_DIM / 2)] = make_float2(y0, y1);
    }
}

extern "C" void kernel_launch(void* const* d_in, const int* in_sizes, int n_in,
                              void* d_out, int out_size, void* d_ws, size_t ws_size,
                              hipStream_t stream) {
    // setup_inputs order: x, latent_growth, latent_seasonal, alpha,
    //                     w_growth, b_growth, w_seasonal, b_seasonal
    const float* x     = (const float*)d_in[0];
    const float* ls    = (const float*)d_in[2];
    const float* alpha = (const float*)d_in[3];
    const float* wmat  = (const float*)d_in[6];
    const float* bias  = (const float*)d_in[7];
    float* out = (float*)d_out;

    u16*   u     = (u16*)d_ws;                                     // 67 MB bf16
    float* e     = (float*)(u + (size_t)B_DIM * N_SEQ * TF_DIM);   // 1 MB
    float* carry = e + (size_t)B_DIM * NCHUNK * TF_DIM;            // 1 MB

    gemm_u_kernel<<<2048, 256, 0, stream>>>(x, ls, wmat, bias, alpha, u, e);

    ema_carry<<<(B_DIM * TF_DIM) / 256, 256, 0, stream>>>(e, alpha, carry);
    ema_apply<<<B_DIM * NCHUNK, 256, 0, stream>>>(u, carry, alpha, out);
}